// Round 1
// baseline (409.658 us; speedup 1.0000x reference)
//
#include <hip/hip_runtime.h>

#define C 64
#define OUTC 64
#define SENT 0x007FFFFFu  // fmap(-inf)

__device__ __forceinline__ unsigned int fmap(float f) {
    unsigned int u = __float_as_uint(f);
    return (u & 0x80000000u) ? ~u : (u | 0x80000000u);
}
__device__ __forceinline__ float funmap(unsigned int u) {
    unsigned int bits = (u & 0x80000000u) ? (u ^ 0x80000000u) : ~u;
    return __uint_as_float(bits);
}

__global__ void init_kernel(unsigned int* __restrict__ ws, int n) {
    int i = blockIdx.x * blockDim.x + threadIdx.x;
    int stride = gridDim.x * blockDim.x;
    for (; i < n; i += stride) ws[i] = SENT;
}

// One wave (64 lanes) per edge; lane = channel.
__global__ void scatter_kernel(const float* __restrict__ x,
                               const int* __restrict__ ei,
                               unsigned int* __restrict__ ws,
                               int E) {
    long long gid = (long long)blockIdx.x * blockDim.x + threadIdx.x;
    int e = (int)(gid >> 6);
    int lane = (int)(gid & 63);
    if (e >= E) return;
    int src = ei[e];
    int dst = ei[E + e];
    float d = x[src * C + lane] - x[dst * C + lane];
    atomicMax(ws + (size_t)dst * C + lane, fmap(d));
}

// One wave per node: out[n] = relu(concat(x[n], xj[n]) @ W + b)
// NOTE: ws may alias out (fallback path) -> no __restrict__ on those.
__global__ void __launch_bounds__(256) mlp_kernel(const float* __restrict__ x,
                                                  const unsigned int* ws,
                                                  const float* __restrict__ W,
                                                  const float* __restrict__ b,
                                                  float* out,
                                                  int N) {
    __shared__ float Wl[128 * OUTC];
    for (int i = threadIdx.x; i < 128 * OUTC; i += blockDim.x)
        Wl[i] = W[i];
    __syncthreads();

    long long gid = (long long)blockIdx.x * blockDim.x + threadIdx.x;
    int n = (int)(gid >> 6);
    int o = (int)(gid & 63);
    if (n >= N) return;

    float xv = x[(size_t)n * C + o];
    unsigned int u = ws[(size_t)n * C + o];
    float xj = (u == SENT) ? 0.0f : funmap(u);

    float acc = b[o];
    #pragma unroll
    for (int k = 0; k < 64; ++k)
        acc = fmaf(__shfl(xv, k), Wl[k * OUTC + o], acc);
    #pragma unroll
    for (int k = 0; k < 64; ++k)
        acc = fmaf(__shfl(xj, k), Wl[(64 + k) * OUTC + o], acc);

    out[(size_t)n * C + o] = fmaxf(acc, 0.0f);
}

extern "C" void kernel_launch(void* const* d_in, const int* in_sizes, int n_in,
                              void* d_out, int out_size, void* d_ws, size_t ws_size,
                              hipStream_t stream) {
    const float* x  = (const float*)d_in[0];
    const int*   ei = (const int*)d_in[1];
    const float* W  = (const float*)d_in[2];
    const float* b  = (const float*)d_in[3];
    float* out = (float*)d_out;

    int N = in_sizes[0] / C;
    int E = in_sizes[1] / 2;

    size_t need = (size_t)N * C * sizeof(unsigned int);
    unsigned int* scratch = (ws_size >= need) ? (unsigned int*)d_ws
                                              : (unsigned int*)d_out;

    init_kernel<<<2048, 256, 0, stream>>>(scratch, N * C);

    long long sthreads = (long long)E * 64;
    int sblocks = (int)((sthreads + 255) / 256);
    scatter_kernel<<<sblocks, 256, 0, stream>>>(x, ei, scratch, E);

    long long mthreads = (long long)N * 64;
    int mblocks = (int)((mthreads + 255) / 256);
    mlp_kernel<<<mblocks, 256, 0, stream>>>(x, scratch, W, b, out, N);
}

// Round 2
// 220.758 us; speedup vs baseline: 1.8557x; 1.8557x over previous
//
#include <hip/hip_runtime.h>

#define SENT 0x007FFFFFu  // fmap(-inf)

typedef __attribute__((ext_vector_type(8))) short bf16x8;
typedef __attribute__((ext_vector_type(4))) float f32x4;

__device__ __forceinline__ unsigned int fmap(float f) {
    unsigned int u = __float_as_uint(f);
    return (u & 0x80000000u) ? ~u : (u | 0x80000000u);
}
__device__ __forceinline__ float funmap(unsigned int u) {
    unsigned int bits = (u & 0x80000000u) ? (u ^ 0x80000000u) : ~u;
    return __uint_as_float(bits);
}
// fp32 -> bf16 round-to-nearest-even
__device__ __forceinline__ short tobf(float f) {
    unsigned int u = __float_as_uint(f);
    u += 0x7FFFu + ((u >> 16) & 1u);
    return (short)(u >> 16);
}

__global__ void init_kernel(uint4* __restrict__ ws, int n4) {
    int i = blockIdx.x * blockDim.x + threadIdx.x;
    int stride = gridDim.x * blockDim.x;
    uint4 v = make_uint4(SENT, SENT, SENT, SENT);
    for (; i < n4; i += stride) ws[i] = v;
}

// One wave (64 lanes) per edge; lane = channel. Pre-check load culls losing atomics.
__global__ void scatter_kernel(const float* __restrict__ x,
                               const int* __restrict__ ei,
                               unsigned int* __restrict__ ws,
                               int E) {
    long long gid = (long long)blockIdx.x * blockDim.x + threadIdx.x;
    int e = (int)(gid >> 6);
    int lane = (int)(gid & 63);
    if (e >= E) return;
    int src = ei[e];
    int dst = ei[E + e];
    float d = x[(size_t)src * 64 + lane] - x[(size_t)dst * 64 + lane];
    unsigned int m = fmap(d);
    unsigned int* p = ws + (size_t)dst * 64 + lane;
    // stale read is safe: skip only when m <= some already-published value
    if (m > *p) atomicMax(p, m);
}

// MFMA MLP: out = relu(concat(x, xj) @ W + b)
// 1 wave = 16 nodes (one 16xK tile). W kept in registers as 16 B-fragments.
// mfma_f32_16x16x32_bf16: A lane l holds A[l&15][(l>>4)*8 + j] (8 contiguous k);
// B lane l holds B[(l>>4)*8 + j][l&15]; D: col=lane&15, row=(lane>>4)*4+reg.
// NOTE: ws may alias out (fallback) -> reads of a tile complete before its stores
// (data dependency through acc), tiles are disjoint -> safe.
__global__ void __launch_bounds__(256) mlp_kernel(const float* __restrict__ x,
                                                  const unsigned int* ws,
                                                  const float* __restrict__ W,
                                                  const float* __restrict__ b,
                                                  float* out,
                                                  int N) {
    int lane = threadIdx.x & 63;
    int wid  = threadIdx.x >> 6;
    int r = lane & 15;   // A row within tile / D col
    int g = lane >> 4;   // 0..3 (k-group / D row-group)

    // B (W) fragments in registers: Bf[nt][kt]; W row-major [128][64]
    bf16x8 Bf[4][4];
    #pragma unroll
    for (int nt = 0; nt < 4; ++nt) {
        #pragma unroll
        for (int kt = 0; kt < 4; ++kt) {
            const float* wp = W + (size_t)(kt * 32 + g * 8) * 64 + nt * 16 + r;
            bf16x8 f;
            #pragma unroll
            for (int j = 0; j < 8; ++j) f[j] = tobf(wp[(size_t)j * 64]);
            Bf[nt][kt] = f;
        }
    }

    float bias[4];
    #pragma unroll
    for (int nt = 0; nt < 4; ++nt) bias[nt] = b[nt * 16 + r];

    int nTiles = N >> 4;                 // N = 100000 -> 6250 exact
    int totalWaves = gridDim.x * 4;
    for (int tile = blockIdx.x * 4 + wid; tile < nTiles; tile += totalWaves) {
        int nodeBase = tile << 4;
        const float* xp = x + (size_t)(nodeBase + r) * 64;
        const unsigned int* wsp = ws + (size_t)(nodeBase + r) * 64;

        bf16x8 Af[4];
        #pragma unroll
        for (int kt = 0; kt < 2; ++kt) {   // k in [0,64): from x
            float4 lo = *(const float4*)(xp + kt * 32 + g * 8);
            float4 hi = *(const float4*)(xp + kt * 32 + g * 8 + 4);
            bf16x8 f;
            f[0] = tobf(lo.x); f[1] = tobf(lo.y); f[2] = tobf(lo.z); f[3] = tobf(lo.w);
            f[4] = tobf(hi.x); f[5] = tobf(hi.y); f[6] = tobf(hi.z); f[7] = tobf(hi.w);
            Af[kt] = f;
        }
        #pragma unroll
        for (int kt = 0; kt < 2; ++kt) {   // k in [64,128): from xj (scatter result)
            uint4 lo = *(const uint4*)(wsp + kt * 32 + g * 8);
            uint4 hi = *(const uint4*)(wsp + kt * 32 + g * 8 + 4);
            unsigned int uu[8] = {lo.x, lo.y, lo.z, lo.w, hi.x, hi.y, hi.z, hi.w};
            bf16x8 f;
            #pragma unroll
            for (int j = 0; j < 8; ++j) {
                float v = (uu[j] == SENT) ? 0.0f : funmap(uu[j]);
                f[j] = tobf(v);
            }
            Af[2 + kt] = f;
        }

        f32x4 acc[4];
        #pragma unroll
        for (int nt = 0; nt < 4; ++nt) {
            f32x4 a = {bias[nt], bias[nt], bias[nt], bias[nt]};
            acc[nt] = a;
        }

        #pragma unroll
        for (int nt = 0; nt < 4; ++nt) {
            #pragma unroll
            for (int kt = 0; kt < 4; ++kt) {
                acc[nt] = __builtin_amdgcn_mfma_f32_16x16x32_bf16(
                    Af[kt], Bf[nt][kt], acc[nt], 0, 0, 0);
            }
        }

        #pragma unroll
        for (int nt = 0; nt < 4; ++nt) {
            #pragma unroll
            for (int reg = 0; reg < 4; ++reg) {
                int nrow = nodeBase + g * 4 + reg;
                out[(size_t)nrow * 64 + nt * 16 + r] = fmaxf(acc[nt][reg], 0.0f);
            }
        }
    }
}

extern "C" void kernel_launch(void* const* d_in, const int* in_sizes, int n_in,
                              void* d_out, int out_size, void* d_ws, size_t ws_size,
                              hipStream_t stream) {
    const float* x  = (const float*)d_in[0];
    const int*   ei = (const int*)d_in[1];
    const float* W  = (const float*)d_in[2];
    const float* b  = (const float*)d_in[3];
    float* out = (float*)d_out;

    int N = in_sizes[0] / 64;
    int E = in_sizes[1] / 2;

    size_t need = (size_t)N * 64 * sizeof(unsigned int);
    unsigned int* scratch = (ws_size >= need) ? (unsigned int*)d_ws
                                              : (unsigned int*)d_out;

    init_kernel<<<2048, 256, 0, stream>>>((uint4*)scratch, N * 16);

    long long sthreads = (long long)E * 64;
    int sblocks = (int)((sthreads + 255) / 256);
    scatter_kernel<<<sblocks, 256, 0, stream>>>(x, ei, scratch, E);

    mlp_kernel<<<782, 256, 0, stream>>>(x, scratch, W, b, out, N);
}

// Round 3
// 199.344 us; speedup vs baseline: 2.0550x; 1.1074x over previous
//
#include <hip/hip_runtime.h>
#include <math.h>

#define SENT 0x007FFFFFu         // fmap(-inf)
#define NEGINF_BITS 0xFF800000u  // raw float -inf

typedef __attribute__((ext_vector_type(8))) short bf16x8;
typedef __attribute__((ext_vector_type(4))) float f32x4;

__device__ __forceinline__ unsigned int fmap(float f) {
    unsigned int u = __float_as_uint(f);
    return (u & 0x80000000u) ? ~u : (u | 0x80000000u);
}
__device__ __forceinline__ float funmap(unsigned int u) {
    unsigned int bits = (u & 0x80000000u) ? (u ^ 0x80000000u) : ~u;
    return __uint_as_float(bits);
}
__device__ __forceinline__ short tobf(float f) {
    unsigned int u = __float_as_uint(f);
    u += 0x7FFFu + ((u >> 16) & 1u);
    return (short)(u >> 16);
}

// ---------------- sort-based path ----------------

__global__ void zero_kernel(unsigned int* __restrict__ p, int n) {
    int i = blockIdx.x * blockDim.x + threadIdx.x;
    int stride = gridDim.x * blockDim.x;
    for (; i < n; i += stride) p[i] = 0u;
}

__global__ void hist_kernel(const int* __restrict__ ei, unsigned int* __restrict__ counts, int E) {
    int i = blockIdx.x * blockDim.x + threadIdx.x;
    int stride = gridDim.x * blockDim.x;
    for (; i < E; i += stride) atomicAdd(&counts[ei[E + i]], 1u);
}

// block-level exclusive scan (1024/block) + block sums
__global__ void __launch_bounds__(1024) scan1_kernel(const unsigned int* __restrict__ counts,
                                                     unsigned int* __restrict__ offs,
                                                     unsigned int* __restrict__ bsum, int N) {
    __shared__ unsigned int s[1024];
    int tid = threadIdx.x;
    int i = blockIdx.x * 1024 + tid;
    unsigned int v = (i < N) ? counts[i] : 0u;
    s[tid] = v;
    __syncthreads();
    for (int d = 1; d < 1024; d <<= 1) {
        unsigned int t = (tid >= d) ? s[tid - d] : 0u;
        __syncthreads();
        s[tid] += t;
        __syncthreads();
    }
    if (i < N) offs[i] = s[tid] - v;          // exclusive within block
    if (tid == 1023) bsum[blockIdx.x] = s[1023];
}

// single-block exclusive scan of block sums (nb <= 1024)
__global__ void __launch_bounds__(1024) scan2_kernel(unsigned int* __restrict__ bsum, int nb) {
    __shared__ unsigned int s[1024];
    int tid = threadIdx.x;
    unsigned int v = (tid < nb) ? bsum[tid] : 0u;
    s[tid] = v;
    __syncthreads();
    for (int d = 1; d < 1024; d <<= 1) {
        unsigned int t = (tid >= d) ? s[tid - d] : 0u;
        __syncthreads();
        s[tid] += t;
        __syncthreads();
    }
    if (tid < nb) bsum[tid] = s[tid] - v;     // exclusive
}

__global__ void scan3_kernel(unsigned int* __restrict__ offs, unsigned int* __restrict__ cursor,
                             const unsigned int* __restrict__ bsum, int N, int E) {
    int i = blockIdx.x * blockDim.x + threadIdx.x;
    int stride = gridDim.x * blockDim.x;
    for (; i < N; i += stride) {
        unsigned int o = offs[i] + bsum[i >> 10];
        offs[i] = o;
        cursor[i] = o;
        if (i == 0) offs[N] = (unsigned int)E;
    }
}

__global__ void place_kernel(const int* __restrict__ ei, unsigned int* __restrict__ cursor,
                             int* __restrict__ ssrc, int E) {
    int i = blockIdx.x * blockDim.x + threadIdx.x;
    int stride = gridDim.x * blockDim.x;
    for (; i < E; i += stride) {
        int dst = ei[E + i];
        unsigned int pos = atomicAdd(&cursor[dst], 1u);
        ssrc[pos] = ei[i];
    }
}

// one wave per node: xj_max[n][c] = max over incoming src of x[src][c]  (-inf if none)
__global__ void __launch_bounds__(256) reduce_kernel(const float* __restrict__ x,
                                                     const unsigned int* __restrict__ offs,
                                                     const int* __restrict__ ssrc,
                                                     float* __restrict__ xj, int N) {
    int lane = threadIdx.x & 63;
    int n = blockIdx.x * 4 + (threadIdx.x >> 6);
    if (n >= N) return;
    int base = (int)offs[n], end = (int)offs[n + 1];
    float m0 = -INFINITY, m1 = -INFINITY, m2 = -INFINITY, m3 = -INFINITY;
    for (int j0 = base; j0 < end; j0 += 64) {
        int cnt = min(64, end - j0);
        int my = (j0 + lane < end) ? ssrc[j0 + lane] : 0;
        int j = 0;
        for (; j + 4 <= cnt; j += 4) {
            int s0 = __shfl(my, j), s1 = __shfl(my, j + 1);
            int s2 = __shfl(my, j + 2), s3 = __shfl(my, j + 3);
            float v0 = x[(size_t)s0 * 64 + lane];
            float v1 = x[(size_t)s1 * 64 + lane];
            float v2 = x[(size_t)s2 * 64 + lane];
            float v3 = x[(size_t)s3 * 64 + lane];
            m0 = fmaxf(m0, v0); m1 = fmaxf(m1, v1);
            m2 = fmaxf(m2, v2); m3 = fmaxf(m3, v3);
        }
        for (; j < cnt; ++j) {
            int s0 = __shfl(my, j);
            m0 = fmaxf(m0, x[(size_t)s0 * 64 + lane]);
        }
    }
    xj[(size_t)n * 64 + lane] = fmaxf(fmaxf(m0, m1), fmaxf(m2, m3));
}

// ---------------- atomic fallback path ----------------

__global__ void init_kernel(uint4* __restrict__ ws, int n4) {
    int i = blockIdx.x * blockDim.x + threadIdx.x;
    int stride = gridDim.x * blockDim.x;
    uint4 v = make_uint4(SENT, SENT, SENT, SENT);
    for (; i < n4; i += stride) ws[i] = v;
}

__global__ void scatter_kernel(const float* __restrict__ x,
                               const int* __restrict__ ei,
                               unsigned int* __restrict__ ws, int E) {
    long long gid = (long long)blockIdx.x * blockDim.x + threadIdx.x;
    int e = (int)(gid >> 6);
    int lane = (int)(gid & 63);
    if (e >= E) return;
    int src = ei[e];
    int dst = ei[E + e];
    unsigned int m = fmap(x[(size_t)src * 64 + lane]);   // max(x[src]) only; -x[dst] folded into MLP
    unsigned int* p = ws + (size_t)dst * 64 + lane;
    if (m > *p) atomicMax(p, m);
}

// ---------------- fused concat-GEMM-ReLU (MFMA) ----------------
// xj array holds per-node max of x[src]; MLP computes xjc = empty ? 0 : (max - x[n][c]).
// MAPPED: xj entries are fmap()-encoded (atomic path) vs raw float with -inf (sort path).
// xj may alias out: each tile's xj reads precede its out stores (data dep through acc).
template <bool MAPPED>
__global__ void __launch_bounds__(256) mlp_kernel(const float* __restrict__ x,
                                                  const unsigned int* xj,
                                                  const float* __restrict__ W,
                                                  const float* __restrict__ b,
                                                  float* out, int N) {
    int lane = threadIdx.x & 63;
    int wid  = threadIdx.x >> 6;
    int r = lane & 15;
    int g = lane >> 4;

    bf16x8 Bf[4][4];
    #pragma unroll
    for (int nt = 0; nt < 4; ++nt)
        #pragma unroll
        for (int kt = 0; kt < 4; ++kt) {
            const float* wp = W + (size_t)(kt * 32 + g * 8) * 64 + nt * 16 + r;
            bf16x8 f;
            #pragma unroll
            for (int j = 0; j < 8; ++j) f[j] = tobf(wp[(size_t)j * 64]);
            Bf[nt][kt] = f;
        }

    float bias[4];
    #pragma unroll
    for (int nt = 0; nt < 4; ++nt) bias[nt] = b[nt * 16 + r];

    int nTiles = (N + 15) >> 4;
    int totalWaves = gridDim.x * 4;
    for (int tile = blockIdx.x * 4 + wid; tile < nTiles; tile += totalWaves) {
        int nodeBase = tile << 4;
        int rowIdx = min(nodeBase + r, N - 1);           // clamp for tail tile
        const float* xp = x + (size_t)rowIdx * 64;
        const unsigned int* jp = xj + (size_t)rowIdx * 64;

        bf16x8 Af[4];
        float xs[2][8];
        #pragma unroll
        for (int kt = 0; kt < 2; ++kt) {                 // k in [0,64): x
            float4 lo = *(const float4*)(xp + kt * 32 + g * 8);
            float4 hi = *(const float4*)(xp + kt * 32 + g * 8 + 4);
            xs[kt][0] = lo.x; xs[kt][1] = lo.y; xs[kt][2] = lo.z; xs[kt][3] = lo.w;
            xs[kt][4] = hi.x; xs[kt][5] = hi.y; xs[kt][6] = hi.z; xs[kt][7] = hi.w;
            bf16x8 f;
            #pragma unroll
            for (int j = 0; j < 8; ++j) f[j] = tobf(xs[kt][j]);
            Af[kt] = f;
        }
        #pragma unroll
        for (int kt = 0; kt < 2; ++kt) {                 // k in [64,128): xj_max - x
            uint4 lo = *(const uint4*)(jp + kt * 32 + g * 8);
            uint4 hi = *(const uint4*)(jp + kt * 32 + g * 8 + 4);
            unsigned int uu[8] = {lo.x, lo.y, lo.z, lo.w, hi.x, hi.y, hi.z, hi.w};
            bf16x8 f;
            #pragma unroll
            for (int j = 0; j < 8; ++j) {
                bool empty;
                float v;
                if (MAPPED) { empty = (uu[j] == SENT); v = funmap(uu[j]); }
                else        { empty = (uu[j] == NEGINF_BITS); v = __uint_as_float(uu[j]); }
                f[j] = tobf(empty ? 0.0f : (v - xs[kt][j]));
            }
            Af[2 + kt] = f;
        }

        f32x4 acc[4];
        #pragma unroll
        for (int nt = 0; nt < 4; ++nt) {
            f32x4 a = {bias[nt], bias[nt], bias[nt], bias[nt]};
            acc[nt] = a;
        }
        #pragma unroll
        for (int nt = 0; nt < 4; ++nt)
            #pragma unroll
            for (int kt = 0; kt < 4; ++kt)
                acc[nt] = __builtin_amdgcn_mfma_f32_16x16x32_bf16(Af[kt], Bf[nt][kt], acc[nt], 0, 0, 0);

        #pragma unroll
        for (int nt = 0; nt < 4; ++nt)
            #pragma unroll
            for (int reg = 0; reg < 4; ++reg) {
                int nrow = nodeBase + g * 4 + reg;
                if (nrow < N)
                    out[(size_t)nrow * 64 + nt * 16 + r] = fmaxf(acc[nt][reg], 0.0f);
            }
    }
}

extern "C" void kernel_launch(void* const* d_in, const int* in_sizes, int n_in,
                              void* d_out, int out_size, void* d_ws, size_t ws_size,
                              hipStream_t stream) {
    const float* x  = (const float*)d_in[0];
    const int*   ei = (const int*)d_in[1];
    const float* W  = (const float*)d_in[2];
    const float* b  = (const float*)d_in[3];
    float* out = (float*)d_out;

    int N = in_sizes[0] / 64;
    int E = in_sizes[1] / 2;
    int nb = (N + 1023) / 1024;          // <= 1024 assumed (N <= 1M)

    size_t xj_b     = (size_t)N * 64 * 4;
    size_t counts_b = (size_t)N * 4;
    size_t offs_b   = (size_t)(N + 1) * 4;
    size_t bsum_b   = (size_t)((nb + 63) & ~63) * 4;
    size_t ssrc_b   = (size_t)E * 4;
    size_t small    = counts_b + offs_b + counts_b + bsum_b + ssrc_b;

    bool sortPath = (ws_size >= small) && (nb <= 1024);
    if (sortPath) {
        char* base = (char*)d_ws;
        unsigned int* xjp;
        if (ws_size >= small + xj_b) { xjp = (unsigned int*)base; base += xj_b; }
        else                         { xjp = (unsigned int*)d_out; }
        unsigned int* counts = (unsigned int*)base; base += counts_b;
        unsigned int* offs   = (unsigned int*)base; base += offs_b;
        unsigned int* cursor = (unsigned int*)base; base += counts_b;
        unsigned int* bsum   = (unsigned int*)base; base += bsum_b;
        int*          ssrc   = (int*)base;

        zero_kernel<<<256, 256, 0, stream>>>(counts, N);
        hist_kernel<<<1024, 256, 0, stream>>>(ei, counts, E);
        scan1_kernel<<<nb, 1024, 0, stream>>>(counts, offs, bsum, N);
        scan2_kernel<<<1, 1024, 0, stream>>>(bsum, nb);
        scan3_kernel<<<256, 256, 0, stream>>>(offs, cursor, bsum, N, E);
        place_kernel<<<1024, 256, 0, stream>>>(ei, cursor, ssrc, E);
        reduce_kernel<<<(N + 3) / 4, 256, 0, stream>>>(x, offs, ssrc, (float*)xjp, N);
        mlp_kernel<false><<<782, 256, 0, stream>>>(x, xjp, W, b, out, N);
    } else {
        // atomic fallback; scratch (or d_out) holds fmap-encoded running max
        size_t need = (size_t)N * 64 * 4;
        unsigned int* scratch = (ws_size >= need) ? (unsigned int*)d_ws : (unsigned int*)d_out;
        init_kernel<<<2048, 256, 0, stream>>>((uint4*)scratch, N * 16);
        long long sthreads = (long long)E * 64;
        int sblocks = (int)((sthreads + 255) / 256);
        scatter_kernel<<<sblocks, 256, 0, stream>>>(x, ei, scratch, E);
        mlp_kernel<true><<<782, 256, 0, stream>>>(x, scratch, W, b, out, N);
    }
}